// Round 5
// baseline (153.439 us; speedup 1.0000x reference)
//
#include <hip/hip_runtime.h>
#include <math.h>

#define EDIM 128
#define BB   256
#define SS   512
#define NWAVE 16
#define BLOCK (NWAVE * 64)
#define REPEAT 8   // attribution probe: 8 full passes, output = mean (identical value)

// DPP-based add: runs on VALU, keeps the DS pipe free.
template<int CTRL>
__device__ __forceinline__ float dpp_add(float v) {
    int r = __builtin_amdgcn_update_dpp(0, __float_as_int(v), CTRL, 0xF, 0xF, true);
    return v + __int_as_float(r);
}

// Sum across the 16 lanes of a DPP row (all 16 lanes get the total).
__device__ __forceinline__ float rowsum16(float v) {
    v = dpp_add<0xB1>(v);    // quad_perm [1,0,3,2]  (xor 1)
    v = dpp_add<0x4E>(v);    // quad_perm [2,3,0,1]  (xor 2)
    v = dpp_add<0x124>(v);   // row_ror:4
    v = dpp_add<0x128>(v);   // row_ror:8
    return v;
}

__global__ __launch_bounds__(BLOCK)
void fused_embed_attn_kernel(const int* __restrict__ x,
                             const float* __restrict__ emb,
                             const float* __restrict__ Wq,
                             const float* __restrict__ bq,
                             const float* __restrict__ Wm,
                             const float* __restrict__ bm,
                             float* __restrict__ out)
{
    const int b    = blockIdx.x;
    const int tid  = threadIdx.x;
    const int wave = tid >> 6;
    const int lane = tid & 63;
    const int row  = lane >> 4;   // 4 token-groups (DPP rows) per wave
    const int slot = lane & 15;   // 16 lanes per token
    const int d0   = slot * 8;    // 8 dims per lane

    const float4 wq0 = *reinterpret_cast<const float4*>(Wq + d0);
    const float4 wq1 = *reinterpret_cast<const float4*>(Wq + d0 + 4);
    const float  bq0 = bq[0];

    __shared__ float sm[NWAVE];
    __shared__ float szv[NWAVE];
    __shared__ float sacc[NWAVE][EDIM];

    float t0a = 0.f, t1a = 0.f;   // accumulated t_hat pair across repeats (wave0)

    for (int r = 0; r < REPEAT; ++r) {
        // rotate token assignment per repeat (defeats cross-repeat CSE;
        // union over waves still covers all 512 tokens exactly once)
        const int tb   = (wave * 32 + row * 8 + r * 64) & (SS - 1);
        const int tbase = b * SS + tb;
        const int4 ia = *reinterpret_cast<const int4*>(x + tbase);
        const int4 ib = *reinterpret_cast<const int4*>(x + tbase + 4);
        const int idx[8] = {ia.x, ia.y, ia.z, ia.w, ib.x, ib.y, ib.z, ib.w};

        float m = -INFINITY, Z = 0.f;
        float acc[8] = {0.f, 0.f, 0.f, 0.f, 0.f, 0.f, 0.f, 0.f};

        #pragma unroll
        for (int i = 0; i < 8; ++i) {
            const float* rp = emb + (size_t)idx[i] * EDIM + d0;
            const float4 e0 = *reinterpret_cast<const float4*>(rp);
            const float4 e1 = *reinterpret_cast<const float4*>(rp + 4);

            float q = e0.x * wq0.x + e0.y * wq0.y + e0.z * wq0.z + e0.w * wq0.w
                    + e1.x * wq1.x + e1.y * wq1.y + e1.z * wq1.z + e1.w * wq1.w;
            float s = e0.x + e0.y + e0.z + e0.w + e1.x + e1.y + e1.z + e1.w;
            q = rowsum16(q);
            s = rowsum16(s);
            const float lp = (q + bq0) * s;

            const float mn = fmaxf(m, lp);
            const float al = __expf(m - mn);
            const float w  = __expf(lp - mn);
            Z = Z * al + w;
            acc[0] = acc[0] * al + w * e0.x;  acc[1] = acc[1] * al + w * e0.y;
            acc[2] = acc[2] * al + w * e0.z;  acc[3] = acc[3] * al + w * e0.w;
            acc[4] = acc[4] * al + w * e1.x;  acc[5] = acc[5] * al + w * e1.y;
            acc[6] = acc[6] * al + w * e1.z;  acc[7] = acc[7] * al + w * e1.w;
            m = mn;
        }

        // merge the wave's 4 row-groups
        float m1 = fmaxf(m, __shfl_xor(m, 16));
        const float M  = fmaxf(m1, __shfl_xor(m1, 32));
        const float sc = __expf(m - M);
        float Zs = Z * sc;
        Zs += __shfl_xor(Zs, 16);
        Zs += __shfl_xor(Zs, 32);
        #pragma unroll
        for (int j = 0; j < 8; ++j) {
            float a = acc[j] * sc;
            a += __shfl_xor(a, 16);
            a += __shfl_xor(a, 32);
            acc[j] = a;
        }

        if (row == 0) {
            *reinterpret_cast<float4*>(&sacc[wave][d0])     = make_float4(acc[0], acc[1], acc[2], acc[3]);
            *reinterpret_cast<float4*>(&sacc[wave][d0 + 4]) = make_float4(acc[4], acc[5], acc[6], acc[7]);
            if (slot == 0) { sm[wave] = M; szv[wave] = Zs; }
        }
        __syncthreads();

        if (tid < 64) {
            float Mb = sm[0];
            #pragma unroll
            for (int w = 1; w < NWAVE; ++w) Mb = fmaxf(Mb, sm[w]);
            float zt = 0.f, tv0 = 0.f, tv1 = 0.f;
            #pragma unroll
            for (int w = 0; w < NWAVE; ++w) {
                const float s2 = __expf(sm[w] - Mb);
                zt += szv[w] * s2;
                const float2 a2 = *reinterpret_cast<const float2*>(&sacc[w][2 * tid]);
                tv0 += a2.x * s2;
                tv1 += a2.y * s2;
            }
            t0a += tv0 / zt;
            t1a += tv1 / zt;
        }
        __syncthreads();   // protect sm/szv/sacc before next repeat overwrites
    }

    // final projection on the averaged t_hat
    if (tid < 64) {
        const float t0 = t0a * (1.0f / REPEAT);
        const float t1 = t1a * (1.0f / REPEAT);
        const float4 wm = *reinterpret_cast<const float4*>(Wm + 4 * tid);
        float c0 = t0 * wm.x + t1 * wm.z;
        float c1 = t0 * wm.y + t1 * wm.w;
        #pragma unroll
        for (int off = 32; off >= 1; off >>= 1) {
            c0 += __shfl_xor(c0, off);
            c1 += __shfl_xor(c1, off);
        }
        if (tid == 0) {
            out[b * 2 + 0] = fmaxf(c0 + bm[0], 0.f);
            out[b * 2 + 1] = fmaxf(c1 + bm[1], 0.f);
        }
    }
}

extern "C" void kernel_launch(void* const* d_in, const int* in_sizes, int n_in,
                              void* d_out, int out_size, void* d_ws, size_t ws_size,
                              hipStream_t stream) {
    const int*   x   = (const int*)  d_in[0];
    const float* emb = (const float*)d_in[1];
    const float* Wq  = (const float*)d_in[2];
    const float* bq  = (const float*)d_in[3];
    const float* Wm  = (const float*)d_in[4];
    const float* bm  = (const float*)d_in[5];
    float* out = (float*)d_out;

    hipLaunchKernelGGL(fused_embed_attn_kernel, dim3(BB), dim3(BLOCK), 0,
                       stream, x, emb, Wq, bq, Wm, bm, out);
}

// Round 6
// 138.509 us; speedup vs baseline: 1.1078x; 1.1078x over previous
//
#include <hip/hip_runtime.h>
#include <math.h>

#define EDIM 128
#define BB   256
#define SS   512
#define NWAVE 16
#define BLOCK (NWAVE * 64)
#define TPG   4            // tokens per 16-lane group (256 tokens / 64 groups)

// DPP-based add: runs on VALU, keeps the DS pipe free.
template<int CTRL>
__device__ __forceinline__ float dpp_add(float v) {
    int r = __builtin_amdgcn_update_dpp(0, __float_as_int(v), CTRL, 0xF, 0xF, true);
    return v + __int_as_float(r);
}

// Sum across the 16 lanes of a DPP row (all 16 lanes get the total).
__device__ __forceinline__ float rowsum16(float v) {
    v = dpp_add<0xB1>(v);    // quad_perm [1,0,3,2]  (xor 1)
    v = dpp_add<0x4E>(v);    // quad_perm [2,3,0,1]  (xor 2)
    v = dpp_add<0x124>(v);   // row_ror:4
    v = dpp_add<0x128>(v);   // row_ror:8
    return v;
}

// ---------------- Phase 1: 512 blocks, each = half a batch row ----------------
// ws layout (floats): M[512] | Z[512] | A[512][128]
__global__ __launch_bounds__(BLOCK, 8)
void partial_kernel(const int* __restrict__ x,
                    const float* __restrict__ emb,
                    const float* __restrict__ Wq,
                    const float* __restrict__ bq,
                    float* __restrict__ ws)
{
    const int part = blockIdx.x;          // 0..511
    const int b    = part >> 1;
    const int half = part & 1;
    const int tid  = threadIdx.x;
    const int wave = tid >> 6;
    const int lane = tid & 63;
    const int row  = lane >> 4;           // 4 groups per wave
    const int slot = lane & 15;
    const int d0   = slot * 8;

    const float4 wq0 = *reinterpret_cast<const float4*>(Wq + d0);
    const float4 wq1 = *reinterpret_cast<const float4*>(Wq + d0 + 4);
    const float  bq0 = bq[0];

    // group owns TPG=4 consecutive tokens
    const int g     = wave * 4 + row;                 // 0..63
    const int tbase = b * SS + half * 256 + g * TPG;
    const int4 iv   = *reinterpret_cast<const int4*>(x + tbase);
    const int idx[TPG] = {iv.x, iv.y, iv.z, iv.w};

    // issue all 8 gather loads up front
    float4 e0[TPG], e1[TPG];
    #pragma unroll
    for (int i = 0; i < TPG; ++i) {
        const float* rp = emb + (size_t)idx[i] * EDIM + d0;
        e0[i] = *reinterpret_cast<const float4*>(rp);
        e1[i] = *reinterpret_cast<const float4*>(rp + 4);
    }

    // two-pass softmax over the 4 register-resident tokens
    float lp[TPG];
    #pragma unroll
    for (int i = 0; i < TPG; ++i) {
        float q = e0[i].x * wq0.x + e0[i].y * wq0.y + e0[i].z * wq0.z + e0[i].w * wq0.w
                + e1[i].x * wq1.x + e1[i].y * wq1.y + e1[i].z * wq1.z + e1[i].w * wq1.w;
        float s = e0[i].x + e0[i].y + e0[i].z + e0[i].w
                + e1[i].x + e1[i].y + e1[i].z + e1[i].w;
        q = rowsum16(q);
        s = rowsum16(s);
        lp[i] = (q + bq0) * s;
    }
    float m = fmaxf(fmaxf(lp[0], lp[1]), fmaxf(lp[2], lp[3]));

    float Z = 0.f;
    float acc[8] = {0.f, 0.f, 0.f, 0.f, 0.f, 0.f, 0.f, 0.f};
    #pragma unroll
    for (int i = 0; i < TPG; ++i) {
        const float w = __expf(lp[i] - m);
        Z += w;
        acc[0] += w * e0[i].x;  acc[1] += w * e0[i].y;
        acc[2] += w * e0[i].z;  acc[3] += w * e0[i].w;
        acc[4] += w * e1[i].x;  acc[5] += w * e1[i].y;
        acc[6] += w * e1[i].z;  acc[7] += w * e1[i].w;
    }

    // merge the wave's 4 row-groups (cross-row shuffles, once)
    float m1 = fmaxf(m, __shfl_xor(m, 16));
    const float M  = fmaxf(m1, __shfl_xor(m1, 32));
    const float sc = __expf(m - M);
    float Zs = Z * sc;
    Zs += __shfl_xor(Zs, 16);
    Zs += __shfl_xor(Zs, 32);
    #pragma unroll
    for (int j = 0; j < 8; ++j) {
        float a = acc[j] * sc;
        a += __shfl_xor(a, 16);
        a += __shfl_xor(a, 32);
        acc[j] = a;
    }

    // block merge of the 16 wave partials
    __shared__ float sm[NWAVE];
    __shared__ float szv[NWAVE];
    __shared__ float sacc[NWAVE][EDIM];

    if (row == 0) {
        *reinterpret_cast<float4*>(&sacc[wave][d0])     = make_float4(acc[0], acc[1], acc[2], acc[3]);
        *reinterpret_cast<float4*>(&sacc[wave][d0 + 4]) = make_float4(acc[4], acc[5], acc[6], acc[7]);
        if (slot == 0) { sm[wave] = M; szv[wave] = Zs; }
    }
    __syncthreads();

    if (tid < EDIM) {
        float Mb = sm[0];
        #pragma unroll
        for (int w = 1; w < NWAVE; ++w) Mb = fmaxf(Mb, sm[w]);
        float zt = 0.f, tv = 0.f;
        #pragma unroll
        for (int w = 0; w < NWAVE; ++w) {
            const float s2 = __expf(sm[w] - Mb);
            zt += szv[w] * s2;
            tv += sacc[w][tid] * s2;
        }
        ws[1024 + part * EDIM + tid] = tv;     // unnormalized, referenced to Mb
        if (tid == 0) { ws[part] = Mb; ws[512 + part] = zt; }
    }
}

// ---------------- Phase 2: merge halves + project + relu ----------------
__global__ __launch_bounds__(64)
void merge_kernel(const float* __restrict__ ws,
                  const float* __restrict__ Wm,
                  const float* __restrict__ bm,
                  float* __restrict__ out)
{
    const int b    = blockIdx.x;
    const int lane = threadIdx.x;

    const float m0 = ws[b * 2],       m1 = ws[b * 2 + 1];
    const float z0 = ws[512 + b * 2], z1 = ws[512 + b * 2 + 1];
    const float M  = fmaxf(m0, m1);
    const float s0 = __expf(m0 - M);
    const float s1 = __expf(m1 - M);
    const float zt = z0 * s0 + z1 * s1;

    const float2 a0 = *reinterpret_cast<const float2*>(ws + 1024 + (b * 2)     * EDIM + 2 * lane);
    const float2 a1 = *reinterpret_cast<const float2*>(ws + 1024 + (b * 2 + 1) * EDIM + 2 * lane);
    const float t0 = (a0.x * s0 + a1.x * s1) / zt;
    const float t1 = (a0.y * s0 + a1.y * s1) / zt;

    const float4 wm = *reinterpret_cast<const float4*>(Wm + 4 * lane);
    float c0 = t0 * wm.x + t1 * wm.z;
    float c1 = t0 * wm.y + t1 * wm.w;
    #pragma unroll
    for (int off = 32; off >= 1; off >>= 1) {
        c0 += __shfl_xor(c0, off);
        c1 += __shfl_xor(c1, off);
    }
    if (lane == 0) {
        out[b * 2 + 0] = fmaxf(c0 + bm[0], 0.f);
        out[b * 2 + 1] = fmaxf(c1 + bm[1], 0.f);
    }
}

extern "C" void kernel_launch(void* const* d_in, const int* in_sizes, int n_in,
                              void* d_out, int out_size, void* d_ws, size_t ws_size,
                              hipStream_t stream) {
    const int*   x   = (const int*)  d_in[0];
    const float* emb = (const float*)d_in[1];
    const float* Wq  = (const float*)d_in[2];
    const float* bq  = (const float*)d_in[3];
    const float* Wm  = (const float*)d_in[4];
    const float* bm  = (const float*)d_in[5];
    float* out = (float*)d_out;
    float* ws  = (float*)d_ws;   // needs (1024 + 512*128)*4 = 266 KB

    hipLaunchKernelGGL(partial_kernel, dim3(2 * BB), dim3(BLOCK), 0, stream,
                       x, emb, Wq, bq, ws);
    hipLaunchKernelGGL(merge_kernel, dim3(BB), dim3(64), 0, stream,
                       ws, Wm, bm, out);
}